// Round 7
// baseline (344.242 us; speedup 1.0000x reference)
//
#include <hip/hip_runtime.h>
#include <stdint.h>

typedef __attribute__((ext_vector_type(8))) short short8;
typedef __attribute__((ext_vector_type(4))) short short4_t;
typedef __attribute__((ext_vector_type(4))) float floatx4;

#define TT 128
#define DD 128

// Barrier waiting only on LDS ops: global loads/stores stay in flight.
#define BARRIER_LDS() asm volatile("s_waitcnt lgkmcnt(0)\n\ts_barrier" ::: "memory")
// Keep the pre-barrier MFMA cluster on its side of the barrier (hipcc can hoist
// register-only MFMAs across asm barriers despite the memory clobber).
#define SFENCE() __builtin_amdgcn_sched_barrier(0)

__device__ __forceinline__ short f2bf(float f) {
  union { float f; uint32_t u; } v; v.f = f;
  uint32_t u = v.u;
  u += 0x7fffu + ((u >> 16) & 1u);   // round-to-nearest-even
  return (short)(u >> 16);
}

__device__ __forceinline__ float sigf(float x) {
  return __builtin_amdgcn_rcpf(1.f + __expf(-x));
}
__device__ __forceinline__ float tanhf_(float x) {
  return 2.f * __builtin_amdgcn_rcpf(1.f + __expf(-2.f * x)) - 1.f;
}

// Transpose+bf16-convert all four weight matrices.
// src fp32 [K][256] (Keras layout) -> dst bf16 [256][K]
__global__ void wtrans_all(const float* __restrict__ W1, const float* __restrict__ U1,
                           const float* __restrict__ W2, const float* __restrict__ U2,
                           short* __restrict__ w1t, short* __restrict__ u1t,
                           short* __restrict__ w2t, short* __restrict__ u2t) {
  int n = blockIdx.x;   // gate column 0..255
  int k = threadIdx.x;  // 0..127
  w1t[n * 128 + k] = f2bf(W1[k * 256 + n]);
  if (k < 64) {
    u1t[n * 64 + k] = f2bf(U1[k * 256 + n]);
    w2t[n * 64 + k] = f2bf(W2[k * 256 + n]);
    u2t[n * 64 + k] = f2bf(U2[k * 256 + n]);
  }
}

// 256 blocks x 8 waves (512 thr), 8 batch rows/block, R0's heterogeneous-wave
// layout (waves 0-3 = layer 1, waves 4-7 = layer 2 lagging one timestep).
// KEY CHANGE vs R0 (131us): the recurrence-independent x@W1 MFMAs (16 of L1's
// 24) move OFF the post-barrier critical path. Iteration i:
//   post-barrier: L1 = read h1(i-1) + 8 U1-MFMAs + gates -> h1(i)
//                 L2 = read h1(i-1),h2(i-2) + 16 MFMAs + gates -> h2(i-1) + out
//   pre-barrier : L1 = read x(i+1) + 16 x-MFMAs into acc for iter i+1
//                 L2 = stage x(i+2) (fp32->bf16) into xbuf
// The pre-barrier x-work overlaps L2's longer post-barrier tail + barrier wait,
// cutting the serial chain from ~2400 to ~1250 cyc/iter (R0-R6 showed all
// pipes <41% busy: latency-bound on the in-wave chain, not any pipe).
// Staging runs 2 steps ahead (prologue stages x(0),x(1) behind 2 barriers).
// Per-acc MFMA order unchanged (x s0..3 then U1 s0..1; W2 s0,s1 then U2 s0,s1)
// -> bit-identical to R0.
// LDS parity (p=i&1), every producer/consumer barrier-separated:
//   hb1[p]  W by L1 iter i (h1(i))  -> R iter i+1 as hb1[1-p']   (B_i between)
//   hb2[p]  W by L2 iter i (h2(i-1))-> R iter i+1 as hb2[1-p']   (B_i between)
//   xbuf[p] W by L2 iter i (x(i+2)) -> R by L1 iter i+1 (x(i+2)) (B_i between)
//   L1 reads xbuf[1-p] (x(i+1)) iter i; L2's same-iter write is xbuf[p]: disjoint.
// i runs 0..TT: L1 computes t=i (i<TT), L2 computes t=i-1 (i>=1).
// LDS strides: hb 80 elems, xbuf 144 -> every access <=2-way banked (free, m136).
// MFMA 16x16x32 bf16 layouts (verified m89/m120):
//   A-frag: A[m=lane&15][k=(lane>>4)*8+j] (+32/kstep)
//   B-frag: B[k=(lane>>4)*8+j][n=lane&15]
//   C/D   : col=lane&15, row=(lane>>4)*4+reg
__global__ __launch_bounds__(512, 2) void lstm_fused(
    const float* __restrict__ x,
    const short* __restrict__ w1t, const short* __restrict__ u1t,
    const short* __restrict__ w2t, const short* __restrict__ u2t,
    const float* __restrict__ b1, const float* __restrict__ b2,
    float* __restrict__ out) {
  __shared__ short hb1[2][8 * 80];
  __shared__ short hb2[2][8 * 80];
  __shared__ short xbuf[2][8 * 144];

  const int tid = threadIdx.x;
  const int w = tid >> 6;
  const bool isL1 = (w < 4);
  const int wg = w & 3;            // gate-column slice within the layer group
  const int lane = tid & 63;
  const int mrow = lane & 15;
  const int quad = lane >> 4;
  const int rowbase = blockIdx.x * 8;
  const int colw = wg * 16 + mrow;
  const int br_a = 2 * (mrow >> 2) + (mrow & 1);  // A-frag batch row (2x dup)

  // ---- weight slices -> registers ----
  // L1: wA[g][0..3]=W1 Ksteps, uA[g][0..1]=U1.
  // L2: wA[g][0..1]=W2, wA[g][2..3]=U2 (uA unused on this path).
  short8 wA[4][4], uA[4][2];
  float bias[4];
  if (isL1) {
#pragma unroll
    for (int g = 0; g < 4; ++g) {
      const int n = g * 4 + wg;
#pragma unroll
      for (int s = 0; s < 4; ++s)
        wA[g][s] = *(const short8*)(w1t + n * 2048 + mrow * 128 + quad * 8 + s * 32);
#pragma unroll
      for (int s = 0; s < 2; ++s)
        uA[g][s] = *(const short8*)(u1t + n * 1024 + mrow * 64 + quad * 8 + s * 32);
      bias[g] = b1[g * 64 + colw];
    }
  } else {
#pragma unroll
    for (int g = 0; g < 4; ++g) {
      const int n = g * 4 + wg;
#pragma unroll
      for (int s = 0; s < 2; ++s) {
        wA[g][s]     = *(const short8*)(w2t + n * 1024 + mrow * 64 + quad * 8 + s * 32);
        wA[g][2 + s] = *(const short8*)(u2t + n * 1024 + mrow * 64 + quad * 8 + s * 32);
      }
      bias[g] = b2[g * 64 + colw];
    }
  }

  // ---- x staging (L2 waves): 256 threads x 4 consecutive floats ----
  const int tid2 = tid & 255;
  const int sxr = tid2 >> 5;          // batch row 0..7
  const int sxc = (tid2 & 31) * 4;    // 4-float group in D=128
  const float* xload = x + (size_t)(rowbase + sxr) * (TT * DD) + sxc;

  short8 h1f[2], xh[4];
  floatx4 acc[4];                      // L1: carries x-part across the barrier
  float cc[2] = {0.f, 0.f};
  floatx4 xn_a, xn_b;                  // staging pipeline: x(i+2), x(i+3)

  // ---- prologue ----
  // zero hb1/hb2 (both parities: h1(-1), h2(-1), h2(-2) reads); stage x(0),x(1).
  for (int idx = tid; idx < 2 * 8 * 80; idx += 512) {
    ((short*)hb1)[idx] = 0;
    ((short*)hb2)[idx] = 0;
  }
  if (!isL1) {
    floatx4 x0 = *(const floatx4*)xload;
    floatx4 x1 = *(const floatx4*)(xload + DD);
    short4_t v;
#pragma unroll
    for (int j = 0; j < 4; ++j) v[j] = f2bf(x0[j]);
    *(short4_t*)&xbuf[0][sxr * 144 + sxc] = v;
#pragma unroll
    for (int j = 0; j < 4; ++j) v[j] = f2bf(x1[j]);
    *(short4_t*)&xbuf[1][sxr * 144 + sxc] = v;
    xn_a = *(const floatx4*)(xload + 2 * DD);
    xn_b = *(const floatx4*)(xload + 3 * DD);
  }
  BARRIER_LDS();
  // L1: precompute x-part of z1(0). Second barrier keeps this xbuf[0] read
  // ordered before L2's iter-0 write of x(2) into xbuf[0].
  if (isL1) {
#pragma unroll
    for (int s = 0; s < 4; ++s)
      xh[s] = *(const short8*)&xbuf[0][br_a * 144 + (quad + 4 * s) * 8];
#pragma unroll
    for (int g = 0; g < 4; ++g) acc[g] = floatx4{0.f, 0.f, 0.f, 0.f};
#pragma unroll
    for (int s = 0; s < 4; ++s)
#pragma unroll
      for (int g = 0; g < 4; ++g)
        acc[g] = __builtin_amdgcn_mfma_f32_16x16x32_bf16(xh[s], wA[g][s], acc[g], 0, 0, 0);
  }
  SFENCE();
  BARRIER_LDS();

  float* outp = out + (size_t)rowbase * 8192 + colw;  // L2 store base

#pragma unroll 1
  for (int i = 0; i <= TT; ++i) {
    const int p = i & 1;

    if (isL1) {
      if (i < TT) {
        // ---- post-barrier critical path: 8 U1-MFMAs + gates ----
        h1f[0] = *(const short8*)&hb1[1 - p][br_a * 80 + quad * 8];
        h1f[1] = *(const short8*)&hb1[1 - p][br_a * 80 + (quad + 4) * 8];
#pragma unroll
        for (int s = 0; s < 2; ++s)
#pragma unroll
          for (int g = 0; g < 4; ++g)
            acc[g] = __builtin_amdgcn_mfma_f32_16x16x32_bf16(h1f[s], uA[g][s], acc[g], 0, 0, 0);
#pragma unroll
        for (int r = 0; r < 2; ++r) {
          float ig = sigf(acc[0][r] + bias[0]);
          float fg = sigf(acc[1][r] + bias[1]);
          float gg = tanhf_(acc[2][r] + bias[2]);
          float og = sigf(acc[3][r] + bias[3]);
          float c = fg * cc[r] + ig * gg;
          cc[r] = c;
          float h = og * tanhf_(c);
          hb1[p][(2 * quad + r) * 80 + colw] = f2bf(h);
        }
      }
      // ---- pre-barrier: x-part of z1(i+1) (recurrence-independent) ----
      if (i <= TT - 2) {
#pragma unroll
        for (int s = 0; s < 4; ++s)
          xh[s] = *(const short8*)&xbuf[1 - p][br_a * 144 + (quad + 4 * s) * 8];
#pragma unroll
        for (int g = 0; g < 4; ++g) acc[g] = floatx4{0.f, 0.f, 0.f, 0.f};
#pragma unroll
        for (int s = 0; s < 4; ++s)
#pragma unroll
          for (int g = 0; g < 4; ++g)
            acc[g] = __builtin_amdgcn_mfma_f32_16x16x32_bf16(xh[s], wA[g][s], acc[g], 0, 0, 0);
      }
    } else {
      if (i >= 1) {
        // ---- post-barrier: z2(i-1) = h1(i-1)@W2 + h2(i-2)@U2 ----
        h1f[0] = *(const short8*)&hb1[1 - p][br_a * 80 + quad * 8];
        h1f[1] = *(const short8*)&hb1[1 - p][br_a * 80 + (quad + 4) * 8];
        short8 g2a = *(const short8*)&hb2[1 - p][br_a * 80 + quad * 8];
        short8 g2b = *(const short8*)&hb2[1 - p][br_a * 80 + (quad + 4) * 8];
#pragma unroll
        for (int g = 0; g < 4; ++g) acc[g] = floatx4{0.f, 0.f, 0.f, 0.f};
#pragma unroll
        for (int s = 0; s < 2; ++s)
#pragma unroll
          for (int g = 0; g < 4; ++g)
            acc[g] = __builtin_amdgcn_mfma_f32_16x16x32_bf16(h1f[s], wA[g][s], acc[g], 0, 0, 0);
#pragma unroll
        for (int g = 0; g < 4; ++g)
          acc[g] = __builtin_amdgcn_mfma_f32_16x16x32_bf16(g2a, wA[g][2], acc[g], 0, 0, 0);
#pragma unroll
        for (int g = 0; g < 4; ++g)
          acc[g] = __builtin_amdgcn_mfma_f32_16x16x32_bf16(g2b, wA[g][3], acc[g], 0, 0, 0);
        const int t = i - 1;
#pragma unroll
        for (int r = 0; r < 2; ++r) {
          float ig = sigf(acc[0][r] + bias[0]);
          float fg = sigf(acc[1][r] + bias[1]);
          float gg = sigf(acc[2][r] + bias[2]);
          float og = sigf(acc[3][r] + bias[3]);
          float c = fg * cc[r] + ig * gg;
          cc[r] = c;
          float h = og * sigf(c);
          hb2[p][(2 * quad + r) * 80 + colw] = f2bf(h);
          outp[(size_t)(2 * quad + r) * 8192 + t * 64] = h;
        }
      }
      // ---- pre-barrier: stage x(i+2) -> xbuf[p]; roll prefetch to x(i+4) ----
      if (i <= TT - 3) {
        short4_t v;
#pragma unroll
        for (int j = 0; j < 4; ++j) v[j] = f2bf(xn_a[j]);
        *(short4_t*)&xbuf[p][sxr * 144 + sxc] = v;
        xn_a = xn_b;
        const int tn = (i + 4 < TT) ? (i + 4) : (TT - 1);
        xn_b = *(const floatx4*)(xload + (size_t)tn * DD);
      }
    }

    SFENCE();
    BARRIER_LDS();  // single barrier per iteration
  }
}

extern "C" void kernel_launch(void* const* d_in, const int* in_sizes, int n_in,
                              void* d_out, int out_size, void* d_ws, size_t ws_size,
                              hipStream_t stream) {
  const float* x  = (const float*)d_in[0];
  const float* W1 = (const float*)d_in[1];
  const float* U1 = (const float*)d_in[2];
  const float* b1 = (const float*)d_in[3];
  const float* W2 = (const float*)d_in[4];
  const float* U2 = (const float*)d_in[5];
  const float* b2 = (const float*)d_in[6];
  float* out = (float*)d_out;

  short* w1t = (short*)d_ws;        // [256][128] bf16
  short* u1t = w1t + 32768;         // [256][64]
  short* w2t = u1t + 16384;         // [256][64]
  short* u2t = w2t + 16384;         // [256][64]

  hipLaunchKernelGGL(wtrans_all, dim3(256), dim3(128), 0, stream,
                     W1, U1, W2, U2, w1t, u1t, w2t, u2t);
  hipLaunchKernelGGL(lstm_fused, dim3(256), dim3(512), 0, stream,
                     x, w1t, u1t, w2t, u2t, b1, b2, out);
}

// Round 8
// 286.092 us; speedup vs baseline: 1.2033x; 1.2033x over previous
//
#include <hip/hip_runtime.h>
#include <stdint.h>

typedef __attribute__((ext_vector_type(8))) short short8;
typedef __attribute__((ext_vector_type(4))) short short4_t;
typedef __attribute__((ext_vector_type(4))) float floatx4;

#define TT 128
#define DD 128

// Barrier waiting only on LDS ops: global loads/stores stay in flight.
#define BARRIER_LDS() asm volatile("s_waitcnt lgkmcnt(0)\n\ts_barrier" ::: "memory")

__device__ __forceinline__ short f2bf(float f) {
  union { float f; uint32_t u; } v; v.f = f;
  uint32_t u = v.u;
  u += 0x7fffu + ((u >> 16) & 1u);   // round-to-nearest-even
  return (short)(u >> 16);
}

__device__ __forceinline__ float sigf(float x) {
  return __builtin_amdgcn_rcpf(1.f + __expf(-x));
}
__device__ __forceinline__ float tanhf_(float x) {
  return 2.f * __builtin_amdgcn_rcpf(1.f + __expf(-2.f * x)) - 1.f;
}

// Transpose+bf16-convert all four weight matrices.
// src fp32 [K][256] (Keras layout) -> dst bf16 [256][K]
__global__ void wtrans_all(const float* __restrict__ W1, const float* __restrict__ U1,
                           const float* __restrict__ W2, const float* __restrict__ U2,
                           short* __restrict__ w1t, short* __restrict__ u1t,
                           short* __restrict__ w2t, short* __restrict__ u2t) {
  int n = blockIdx.x;   // gate column 0..255
  int k = threadIdx.x;  // 0..127
  w1t[n * 128 + k] = f2bf(W1[k * 256 + n]);
  if (k < 64) {
    u1t[n * 64 + k] = f2bf(U1[k * 256 + n]);
    w2t[n * 64 + k] = f2bf(W2[k * 256 + n]);
    u2t[n * 64 + k] = f2bf(U2[k * 256 + n]);
  }
}

// 256 blocks x 8 waves (512 thr), 8 batch rows/block. HETEROGENEOUS waves:
//   waves 0-3: layer 1 only (gate-split over hidden cols, W1/U1 in regs, 24 MFMA)
//   waves 4-7: layer 2 only (W2/U2 in regs, 16 MFMA), lagging ONE timestep,
//              plus x(t+1) fp32->bf16 staging (they're the lighter waves).
// This is the verified R0/R6 structure (130.0us). R1-R7 established that on
// the same SIMD, MFMA and VALU execution are ADDITIVE (per-iter busy cycles
// invariant across all restructures): iteration = MFMA(776) + VALU(~900) +
// overhead(~700). Scheduling cannot win; this round trims the overhead slice
// only: #pragma unroll 2 over the timestep loop constant-folds all parity
// (p / 1-p) buffer selects and parity-dependent LDS addressing, and halves
// loop-branch overhead. No change to dataflow, accumulation order, rounding,
// or barrier count -> bit-identical output.
// Batch rows at M-rows {0,1,4,5,8,9,12,13} (br_a = 2*(mrow>>2)+(mrow&1)):
// C-regs 0,1 of quad q = real rows 2q,2q+1 -> elementwise 2 elems/lane.
// One lgkm-only barrier/iteration; hb1/hb2/xbuf parity double-buffered.
// i runs 0..TT: L1 computes t=i (skip i=TT), L2 computes t=i-1 (skip i=0).
// LDS strides: hb 80 elems, xbuf 144 -> every access <=2-way banked (free, m136).
// MFMA 16x16x32 bf16 layouts (verified m89/m120):
//   A-frag: A[m=lane&15][k=(lane>>4)*8+j] (+32/kstep)
//   B-frag: B[k=(lane>>4)*8+j][n=lane&15]
//   C/D   : col=lane&15, row=(lane>>4)*4+reg
__global__ __launch_bounds__(512, 2) void lstm_fused(
    const float* __restrict__ x,
    const short* __restrict__ w1t, const short* __restrict__ u1t,
    const short* __restrict__ w2t, const short* __restrict__ u2t,
    const float* __restrict__ b1, const float* __restrict__ b2,
    float* __restrict__ out) {
  __shared__ short hb1[2][8 * 80];
  __shared__ short hb2[2][8 * 80];
  __shared__ short xbuf[2][8 * 144];

  const int tid = threadIdx.x;
  const int w = tid >> 6;
  const bool isL1 = (w < 4);
  const int wg = w & 3;            // gate-column slice within the layer group
  const int lane = tid & 63;
  const int mrow = lane & 15;
  const int quad = lane >> 4;
  const int rowbase = blockIdx.x * 8;
  const int colw = wg * 16 + mrow;
  const int br_a = 2 * (mrow >> 2) + (mrow & 1);  // A-frag batch row (2x dup)

  // ---- weight slices -> registers ----
  // L1: wA[g][0..3]=W1 Ksteps, uA[g][0..1]=U1.
  // L2: wA[g][0..1]=W2, wA[g][2..3]=U2 (uA unused on this path).
  short8 wA[4][4], uA[4][2];
  float bias[4];
  if (isL1) {
#pragma unroll
    for (int g = 0; g < 4; ++g) {
      const int n = g * 4 + wg;
#pragma unroll
      for (int s = 0; s < 4; ++s)
        wA[g][s] = *(const short8*)(w1t + n * 2048 + mrow * 128 + quad * 8 + s * 32);
#pragma unroll
      for (int s = 0; s < 2; ++s)
        uA[g][s] = *(const short8*)(u1t + n * 1024 + mrow * 64 + quad * 8 + s * 32);
      bias[g] = b1[g * 64 + colw];
    }
  } else {
#pragma unroll
    for (int g = 0; g < 4; ++g) {
      const int n = g * 4 + wg;
#pragma unroll
      for (int s = 0; s < 2; ++s) {
        wA[g][s]     = *(const short8*)(w2t + n * 1024 + mrow * 64 + quad * 8 + s * 32);
        wA[g][2 + s] = *(const short8*)(u2t + n * 1024 + mrow * 64 + quad * 8 + s * 32);
      }
      bias[g] = b2[g * 64 + colw];
    }
  }

  // ---- x staging (L2 waves): 256 threads x 4 consecutive floats ----
  const int tid2 = tid & 255;
  const int sxr = tid2 >> 5;          // batch row 0..7
  const int sxc = (tid2 & 31) * 4;    // 4-float group in D=128
  const float* xload = x + (size_t)(rowbase + sxr) * (TT * DD) + sxc;

  // h1f: h1(t-1) A-frags (both groups). xh: L1 = x(t) A-frags; L2 = h2(t-2) A-frags.
  short8 h1f[2], xh[4];
#pragma unroll
  for (int s = 0; s < 2; ++s)
#pragma unroll
    for (int j = 0; j < 8; ++j) h1f[s][j] = 0;
#pragma unroll
  for (int s = 0; s < 4; ++s)
#pragma unroll
    for (int j = 0; j < 8; ++j) xh[s][j] = 0;
  float cc[2] = {0.f, 0.f};
  floatx4 xnext;

  // ---- prologue: zero hb2 (h2(-1)=0 read at i=0), stage x(0), prefetch x(1) ----
  for (int idx = tid; idx < 2 * 8 * 80; idx += 512) ((short*)hb2)[idx] = 0;
  if (!isL1) {
    floatx4 x0 = *(const floatx4*)xload;
    short4_t v;
#pragma unroll
    for (int j = 0; j < 4; ++j) v[j] = f2bf(x0[j]);
    *(short4_t*)&xbuf[0][sxr * 144 + sxc] = v;
    xnext = *(const floatx4*)(xload + DD);
  }
  BARRIER_LDS();
  if (isL1) {
#pragma unroll
    for (int s = 0; s < 4; ++s)
      xh[s] = *(const short8*)&xbuf[0][br_a * 144 + (quad + 4 * s) * 8];
  }

  float* outp = out + (size_t)rowbase * 8192 + colw;  // L2 store base

#pragma unroll 2
  for (int i = 0; i <= TT; ++i) {
    const int p = i & 1;

    if (isL1) {
      if (i < TT) {
        // z1(i) = x(i) @ W1 + h1(i-1) @ U1
        floatx4 acc[4];
#pragma unroll
        for (int g = 0; g < 4; ++g) acc[g] = floatx4{0.f, 0.f, 0.f, 0.f};
#pragma unroll
        for (int g = 0; g < 4; ++g) {
#pragma unroll
          for (int s = 0; s < 4; ++s)
            acc[g] = __builtin_amdgcn_mfma_f32_16x16x32_bf16(xh[s], wA[g][s], acc[g], 0, 0, 0);
#pragma unroll
          for (int s = 0; s < 2; ++s)
            acc[g] = __builtin_amdgcn_mfma_f32_16x16x32_bf16(h1f[s], uA[g][s], acc[g], 0, 0, 0);
        }
#pragma unroll
        for (int r = 0; r < 2; ++r) {
          float ig = sigf(acc[0][r] + bias[0]);
          float fg = sigf(acc[1][r] + bias[1]);
          float gg = tanhf_(acc[2][r] + bias[2]);
          float og = sigf(acc[3][r] + bias[3]);
          float c = fg * cc[r] + ig * gg;
          cc[r] = c;
          float h = og * tanhf_(c);
          hb1[p][(2 * quad + r) * 80 + colw] = f2bf(h);
        }
      }
    } else {
      // stage x(i+1) -> xbuf[1-p]; prefetch x(min(i+2,TT-1))
      {
        short4_t v;
#pragma unroll
        for (int j = 0; j < 4; ++j) v[j] = f2bf(xnext[j]);
        *(short4_t*)&xbuf[1 - p][sxr * 144 + sxc] = v;
        int tn = (i + 2 < TT) ? i + 2 : TT - 1;
        xnext = *(const floatx4*)(xload + (size_t)tn * DD);
      }
      if (i >= 1) {
        // z2(i-1) = h1(i-1) @ W2 + h2(i-2) @ U2
        floatx4 acc[4];
#pragma unroll
        for (int g = 0; g < 4; ++g) acc[g] = floatx4{0.f, 0.f, 0.f, 0.f};
#pragma unroll
        for (int g = 0; g < 4; ++g) {
#pragma unroll
          for (int s = 0; s < 2; ++s)
            acc[g] = __builtin_amdgcn_mfma_f32_16x16x32_bf16(h1f[s], wA[g][s], acc[g], 0, 0, 0);
#pragma unroll
          for (int s = 0; s < 2; ++s)
            acc[g] = __builtin_amdgcn_mfma_f32_16x16x32_bf16(xh[s], wA[g][2 + s], acc[g], 0, 0, 0);
        }
#pragma unroll
        for (int r = 0; r < 2; ++r) {
          float ig = sigf(acc[0][r] + bias[0]);
          float fg = sigf(acc[1][r] + bias[1]);
          float gg = sigf(acc[2][r] + bias[2]);
          float og = sigf(acc[3][r] + bias[3]);
          float c = fg * cc[r] + ig * gg;
          cc[r] = c;
          float h = og * sigf(c);
          hb2[p][(2 * quad + r) * 80 + colw] = f2bf(h);
          outp[(size_t)(2 * quad + r) * 8192 + (i - 1) * 64] = h;
        }
      }
    }

    BARRIER_LDS();  // single barrier per iteration

    if (i < TT) {
      if (isL1) {
#pragma unroll
        for (int s = 0; s < 2; ++s)
          h1f[s] = *(const short8*)&hb1[p][br_a * 80 + (quad + 4 * s) * 8];
#pragma unroll
        for (int s = 0; s < 4; ++s)
          xh[s] = *(const short8*)&xbuf[1 - p][br_a * 144 + (quad + 4 * s) * 8];
      } else {
#pragma unroll
        for (int s = 0; s < 2; ++s) {
          h1f[s] = *(const short8*)&hb1[p][br_a * 80 + (quad + 4 * s) * 8];
          xh[s]  = *(const short8*)&hb2[p][br_a * 80 + (quad + 4 * s) * 8];
        }
      }
    }
  }
}

extern "C" void kernel_launch(void* const* d_in, const int* in_sizes, int n_in,
                              void* d_out, int out_size, void* d_ws, size_t ws_size,
                              hipStream_t stream) {
  const float* x  = (const float*)d_in[0];
  const float* W1 = (const float*)d_in[1];
  const float* U1 = (const float*)d_in[2];
  const float* b1 = (const float*)d_in[3];
  const float* W2 = (const float*)d_in[4];
  const float* U2 = (const float*)d_in[5];
  const float* b2 = (const float*)d_in[6];
  float* out = (float*)d_out;

  short* w1t = (short*)d_ws;        // [256][128] bf16
  short* u1t = w1t + 32768;         // [256][64]
  short* w2t = u1t + 16384;         // [256][64]
  short* u2t = w2t + 16384;         // [256][64]

  hipLaunchKernelGGL(wtrans_all, dim3(256), dim3(128), 0, stream,
                     W1, U1, W2, U2, w1t, u1t, w2t, u2t);
  hipLaunchKernelGGL(lstm_fused, dim3(256), dim3(512), 0, stream,
                     x, w1t, u1t, w2t, u2t, b1, b2, out);
}